// Round 3
// baseline (143.853 us; speedup 1.0000x reference)
//
#include <hip/hip_runtime.h>

#define NN 16384
#define NE 262144

// ---------------------------------------------------------------------------
// prep: per layer. One wave per node.
//  - G[v][s][o] = sum_i h[v][i] * Ws[i*32+o], s=0..7 from Wk, s=8 from bk
//  - agg[v][o]  = sum_i h[v][i] * root[i*32+o] + b[o]   (edge scatter adds on top)
// h = hin[v*stride + i], optionally relu'd (layer 2 reads layer-1 agg in place).
// Lane layout: o = lane&31, half = lane>>5; each lane owns 5 weight slices
// (160 VGPRs), h broadcast across lanes via __shfl.
// ---------------------------------------------------------------------------
__global__ __launch_bounds__(256) void prep_kernel(
    const float* __restrict__ hin, int in_stride, int apply_relu,
    const float* __restrict__ Wk, const float* __restrict__ bk,
    const float* __restrict__ root, const float* __restrict__ bvec,
    float* __restrict__ G, float* __restrict__ agg, int n)
{
    int gtid = blockIdx.x * blockDim.x + threadIdx.x;
    int wid  = gtid >> 6;
    int nw   = (gridDim.x * blockDim.x) >> 6;
    int lane = threadIdx.x & 63;
    int o    = lane & 31;
    int half = lane >> 5;

    // slices: half==0 -> s=0..4 ; half==1 -> s=5..9 (s==8 is bk, s==9 is root)
    float w[5][32];
#pragma unroll
    for (int k = 0; k < 5; ++k) {
        int s = half * 5 + k;
        const float* Ws = (s < 8) ? (Wk + s * 1024) : ((s == 8) ? bk : root);
#pragma unroll
        for (int i = 0; i < 32; ++i) w[k][i] = Ws[i * 32 + o];
    }
    float bo = bvec[o];

    for (int v = wid; v < n; v += nw) {
        float hv = hin[(size_t)v * in_stride + o];
        if (apply_relu) hv = fmaxf(hv, 0.0f);
        float acc0 = 0.f, acc1 = 0.f, acc2 = 0.f, acc3 = 0.f, acc4 = 0.f;
#pragma unroll
        for (int i = 0; i < 32; ++i) {
            float hi = __shfl(hv, i, 64);   // lane i (<32) broadcast to all 64
            acc0 = fmaf(hi, w[0][i], acc0);
            acc1 = fmaf(hi, w[1][i], acc1);
            acc2 = fmaf(hi, w[2][i], acc2);
            acc3 = fmaf(hi, w[3][i], acc3);
            acc4 = fmaf(hi, w[4][i], acc4);
        }
        float* Gv = G + (size_t)v * 288;
        if (half == 0) {
            Gv[0 * 32 + o] = acc0;
            Gv[1 * 32 + o] = acc1;
            Gv[2 * 32 + o] = acc2;
            Gv[3 * 32 + o] = acc3;
            Gv[4 * 32 + o] = acc4;
        } else {
            Gv[5 * 32 + o] = acc0;
            Gv[6 * 32 + o] = acc1;
            Gv[7 * 32 + o] = acc2;
            Gv[8 * 32 + o] = acc3;            // bias slice (coefficient 1)
            agg[(size_t)v * 32 + o] = acc4 + bo;  // root product + b
        }
    }
}

// ---------------------------------------------------------------------------
// edge scatter: half-wave (32 lanes) per edge.
// m[o] = G[src][8][o] + sum_{s<8} e[ed][s] * G[src][s][o]; atomicAdd to agg[tgt].
// ---------------------------------------------------------------------------
__global__ __launch_bounds__(256) void edge_kernel(
    const float* __restrict__ efeat, const int* __restrict__ src,
    const int* __restrict__ tgt, const float* __restrict__ G,
    float* __restrict__ agg, int ne)
{
    int gtid = blockIdx.x * blockDim.x + threadIdx.x;
    int o    = gtid & 31;
    int hw   = gtid >> 5;
    int nhw  = (gridDim.x * blockDim.x) >> 5;

    for (int ei = hw; ei < ne; ei += nhw) {
        int s = src[ei];
        int t = tgt[ei];
        const float4* pe = (const float4*)(efeat + (size_t)ei * 8);
        float4 ea = pe[0];
        float4 eb = pe[1];
        const float* g = G + (size_t)s * 288;
        float m = g[8 * 32 + o];
        m = fmaf(ea.x, g[0 * 32 + o], m);
        m = fmaf(ea.y, g[1 * 32 + o], m);
        m = fmaf(ea.z, g[2 * 32 + o], m);
        m = fmaf(ea.w, g[3 * 32 + o], m);
        m = fmaf(eb.x, g[4 * 32 + o], m);
        m = fmaf(eb.y, g[5 * 32 + o], m);
        m = fmaf(eb.z, g[6 * 32 + o], m);
        m = fmaf(eb.w, g[7 * 32 + o], m);
        atomicAdd(agg + (size_t)t * 32 + o, m);
    }
}

__global__ void init_pooled(float* __restrict__ pooled)
{
    int t = threadIdx.x;
    if (t < 32) pooled[t] = 0.0f;
}

// pool: pooled[o] = sum_v relu(agg[v][o])
__global__ __launch_bounds__(256) void pool_kernel(
    const float* __restrict__ agg, float* __restrict__ pooled, int n)
{
    int gtid  = blockIdx.x * blockDim.x + threadIdx.x;
    int o     = gtid & 31;
    int row0  = gtid >> 5;
    int nrows = (gridDim.x * blockDim.x) >> 5;
    float sum = 0.0f;
    for (int v = row0; v < n; v += nrows)
        sum += fmaxf(agg[(size_t)v * 32 + o], 0.0f);
    sum += __shfl_xor(sum, 32, 64);           // pair lanes (l, l+32): same o
    if ((threadIdx.x & 63) < 32) atomicAdd(pooled + o, sum);
}

// out = relu(pooled . Wd + bd)
__global__ void final_kernel(const float* __restrict__ pooled,
                             const float* __restrict__ Wd,
                             const float* __restrict__ bd,
                             float* __restrict__ out)
{
    int lane = threadIdx.x;
    float v = (lane < 32) ? pooled[lane] * Wd[lane] : 0.0f;
#pragma unroll
    for (int k = 32; k >= 1; k >>= 1) v += __shfl_xor(v, k, 64);
    if (lane == 0) out[0] = fmaxf(v + bd[0], 0.0f);
}

extern "C" void kernel_launch(void* const* d_in, const int* in_sizes, int n_in,
                              void* d_out, int out_size, void* d_ws, size_t ws_size,
                              hipStream_t stream)
{
    const float* x     = (const float*)d_in[0];   // (N,33), last col = 1 (excluded)
    const int*   src   = (const int*)d_in[1];
    const int*   tgt   = (const int*)d_in[2];
    const float* e     = (const float*)d_in[3];   // (E,8)
    const float* Wk1   = (const float*)d_in[4];   // (8,1024)
    const float* bk1   = (const float*)d_in[5];   // (1024)
    const float* root1 = (const float*)d_in[6];   // (32,32)
    const float* b1    = (const float*)d_in[7];   // (32)
    const float* Wk2   = (const float*)d_in[8];
    const float* bk2   = (const float*)d_in[9];
    const float* root2 = (const float*)d_in[10];
    const float* b2    = (const float*)d_in[11];
    const float* Wd    = (const float*)d_in[12];  // (32,1)
    const float* bd    = (const float*)d_in[13];  // (1)
    float* out = (float*)d_out;

    // workspace layout: agg (N*32 f32 = 2 MB) | pooled (32 f32, 256B slot) | G (N*288 f32 = 18.9 MB)
    char*  ws     = (char*)d_ws;
    float* agg    = (float*)ws;
    float* pooled = (float*)(ws + (size_t)NN * 32 * 4);
    float* G      = (float*)(ws + (size_t)NN * 32 * 4 + 256);

    init_pooled<<<1, 64, 0, stream>>>(pooled);

    // layer 1: h = x[:, :32]
    prep_kernel<<<512, 256, 0, stream>>>(x, 33, 0, Wk1, bk1, root1, b1, G, agg, NN);
    edge_kernel<<<8192, 256, 0, stream>>>(e, src, tgt, G, agg, NE);

    // layer 2: h = relu(agg) applied on load; agg rewritten in place (same-wave safe)
    prep_kernel<<<512, 256, 0, stream>>>(agg, 32, 1, Wk2, bk2, root2, b2, G, agg, NN);
    edge_kernel<<<8192, 256, 0, stream>>>(e, src, tgt, G, agg, NE);

    // pooled = sum_v relu(agg); out = relu(pooled . Wd + bd)
    pool_kernel<<<64, 256, 0, stream>>>(agg, pooled, NN);
    final_kernel<<<1, 64, 0, stream>>>(pooled, Wd, bd, out);
}